// Round 2
// baseline (314.084 us; speedup 1.0000x reference)
//
#include <hip/hip_runtime.h>
#include <hip/hip_bf16.h>

typedef __attribute__((ext_vector_type(8))) short bf16x8;
typedef __attribute__((ext_vector_type(4))) float f32x4;

#define CAP 64      // fixed per-node edge slot capacity (deg>CAP -> exact fallback)
#define SH  8       // dst shards (== XCD count; blockIdx%8 ~ XCD heuristic)
#define SLICES 4    // feature planes: 32 feats (64B) each, CONTIGUOUS 3.2MB -> L2-resident

// fp32 -> bf16 (round-to-nearest-even), bit pattern as ushort
static __device__ inline unsigned short f2b(float f) {
    unsigned u = __float_as_uint(f);
    unsigned r = (u + 0x7FFFu + ((u >> 16) & 1u)) >> 16;
    return (unsigned short)r;
}
// packed bf16 pair -> two fp32
static __device__ inline float blo(unsigned u) { return __uint_as_float(u << 16); }
static __device__ inline float bhi(unsigned u) { return __uint_as_float(u & 0xFFFF0000u); }

// ---------------------------------------------------------------------------
__global__ void zero_kernel(int* __restrict__ p, int n) {
    int i = blockIdx.x * blockDim.x + threadIdx.x;
    if (i < n) p[i] = 0;
}

// ---------------------------------------------------------------------------
// XCD-sharded slot fill (unchanged from round 0). cursor[d] ends == in-degree.
// ---------------------------------------------------------------------------
__global__ __launch_bounds__(256) void fill_shard_kernel(
        const int* __restrict__ ei, int* __restrict__ cursor,
        unsigned short* __restrict__ edge16, int E, int N, int G, int npg) {
    int s = blockIdx.x & (SH - 1);
    int i = blockIdx.x >> 3;
    int d_lo = s * npg;
    int d_hi = d_lo + npg; if (d_hi > N) d_hi = N;
    int C = (E + G - 1) / G;
    int e0 = i * C;
    int e1 = e0 + C; if (e1 > E) e1 = E;
    for (int e = e0 + threadIdx.x; e < e1; e += 256) {
        int d = ei[E + e];
        if (d < d_lo || d >= d_hi) continue;
        int src = ei[e];
        if ((unsigned)src >= (unsigned)N) src = 0;   // defensive
        int pos = atomicAdd(&cursor[d], 1);
        if (pos < CAP) edge16[(size_t)d * CAP + pos] = (unsigned short)src;
    }
}

// ---------------------------------------------------------------------------
// fp32 x [N][128] -> bf16 PLANES xb[plane][node][32]. One float4 -> ushort4.
// i indexes (node, chunk-of-4-feats): node=i>>5, c=i&31; plane=c>>3, w=c&7.
// ---------------------------------------------------------------------------
__global__ __launch_bounds__(256) void x2b_kernel(const float* __restrict__ x,
                                                  unsigned short* __restrict__ xb,
                                                  int n32, int N) {
    int i = blockIdx.x * blockDim.x + threadIdx.x;
    if (i >= n32) return;
    int node = i >> 5;
    int c = i & 31;
    float4 v = ((const float4*)x)[i];
    ushort4 b;
    b.x = f2b(v.x); b.y = f2b(v.y); b.z = f2b(v.z); b.w = f2b(v.w);
    ((ushort4*)(xb + (size_t)(c >> 3) * N * 32 + node * 32 + (c & 7) * 4))[0] = b;
}

// ---------------------------------------------------------------------------
// PLANE-SLICED mean aggregation (fp32 accumulate, bf16 plane out).
// slice = blockIdx.x / nb4 (slow-varying -> concurrent blocks share one plane;
// plane = N*64B = 3.2MB CONTIGUOUS -> resident in each XCD's 4MB L2).
// One wave per node; lane = g*4 + f: group g in [0,16) handles edge j+g,
// lane f in [0,4) covers 8 feats via one uint4 (16B) gather -> same per-byte
// VALU cost as the round-0 full-row kernel, 1/4 the working set.
// Cross-group reduce: shfl_xor 4,8,16,32.
// ---------------------------------------------------------------------------
__global__ __launch_bounds__(256) void aggregate_kernel(
        const unsigned short* __restrict__ in, const int* __restrict__ cursor,
        const unsigned short* __restrict__ edge16, const int* __restrict__ ei,
        unsigned short* __restrict__ agg, int E, int N, int nb4) {
    int slice = blockIdx.x / nb4;              // 0..SLICES-1, slow-varying
    int blk   = blockIdx.x - slice * nb4;
    int node  = blk * 4 + (threadIdx.x >> 6);
    if (node >= N) return;
    int lane = threadIdx.x & 63;
    int g = lane >> 2;          // edge group 0..15
    int f = lane & 3;           // 16B chunk within 64B plane row
    int deg = cursor[node];

    float acc[8];
    #pragma unroll
    for (int i = 0; i < 8; ++i) acc[i] = 0.f;
    const unsigned short* inS = in + (size_t)slice * N * 32;   // plane base

    if (deg <= CAP) {
        const unsigned short* base = edge16 + (size_t)node * CAP;
        int idx = (lane < deg) ? (int)base[lane] : 0;   // coalesced ushort preload
        #pragma unroll 2
        for (int j = 0; j < deg; j += 16) {
            int e = j + g;
            int s = __shfl(idx, e & 63);
            if (e < deg) {
                uint4 v = *(const uint4*)(inS + s * 32 + f * 8);
                acc[0] += blo(v.x); acc[1] += bhi(v.x);
                acc[2] += blo(v.y); acc[3] += bhi(v.y);
                acc[4] += blo(v.z); acc[5] += bhi(v.z);
                acc[6] += blo(v.w); acc[7] += bhi(v.w);
            }
        }
    } else {
        // exact fallback: scan the whole edge list for this node (this plane)
        for (int j = 0; j < E; j += 16) {
            int e = j + g;
            bool act = (e < E) && (ei[E + e] == node);
            if (act) {
                int s = ei[e];
                if ((unsigned)s >= (unsigned)N) s = 0;
                uint4 v = *(const uint4*)(inS + s * 32 + f * 8);
                acc[0] += blo(v.x); acc[1] += bhi(v.x);
                acc[2] += blo(v.y); acc[3] += bhi(v.y);
                acc[4] += blo(v.z); acc[5] += bhi(v.z);
                acc[6] += blo(v.w); acc[7] += bhi(v.w);
            }
        }
    }

    // reduce across the 16 edge-groups (xor lanes 4, 8, 16, 32)
    #pragma unroll
    for (int d = 4; d <= 32; d <<= 1) {
        #pragma unroll
        for (int i = 0; i < 8; ++i) acc[i] += __shfl_xor(acc[i], d);
    }

    if (g == 0) {
        float inv = 1.0f / (float)(deg > 1 ? deg : 1);
        uint4 o;
        o.x = (unsigned)f2b(acc[0] * inv) | ((unsigned)f2b(acc[1] * inv) << 16);
        o.y = (unsigned)f2b(acc[2] * inv) | ((unsigned)f2b(acc[3] * inv) << 16);
        o.z = (unsigned)f2b(acc[4] * inv) | ((unsigned)f2b(acc[5] * inv) << 16);
        o.w = (unsigned)f2b(acc[6] * inv) | ((unsigned)f2b(acc[7] * inv) << 16);
        *(uint4*)(agg + (size_t)slice * N * 32 + node * 32 + f * 8) = o;
    }
}

// ---------------------------------------------------------------------------
// Weight prep (unchanged): Wt[layer][n][k] bf16, k-contiguous.
// ---------------------------------------------------------------------------
__global__ void prep_w_kernel(const float* __restrict__ W1l, const float* __restrict__ W1r,
                              const float* __restrict__ W2l, const float* __restrict__ W2r,
                              unsigned short* __restrict__ wt) {
    int n = blockIdx.x & 127;
    int layer = blockIdx.x >> 7;
    int k = threadIdx.x;           // 0..127
    const float* Wlp = layer ? W2l : W1l;
    const float* Wrp = layer ? W2r : W1r;
    unsigned short* dst = wt + (size_t)layer * 128 * 256 + (size_t)n * 256;
    dst[k]       = f2b(Wlp[(size_t)k * 128 + n]);
    dst[k + 128] = f2b(Wrp[(size_t)k * 128 + n]);
}

// ---------------------------------------------------------------------------
// MFMA GEMM over PLANE inputs: out[i,:] = (agg[i,:] || x[i,:]) @ Wt^T + bias.
// A and X arrive as 4 planes each ([plane][node][32] bf16, stride n*32).
// Stage gathers 16B chunks: q<16 -> A plane q>>2, q>=16 -> X plane (q-16)>>2.
// OUT_BF16=1: writes h in PLANE layout (aliases X planes; block-private rows
// staged to LDS before any store). OUT_BF16=0: fp32 row-major final out.
// ---------------------------------------------------------------------------
template<int RELU, int OUT_BF16>
__global__ __launch_bounds__(256) void gemm_mfma_kernel(
        const unsigned short* __restrict__ Arow, const unsigned short* __restrict__ Xrow,
        const unsigned short* __restrict__ Wt, const float* __restrict__ bias,
        void* __restrict__ outp, int n) {
    constexpr int LDK = 264;
    __shared__ unsigned short sA[64 * LDK];
    int tid = threadIdx.x;
    int row0 = blockIdx.x * 64;
    int ps = n * 32;                 // plane stride (shorts)

    // stage 64 rows x 256 bf16 = 2048 x 16B chunks, 8/thread
    #pragma unroll
    for (int it = 0; it < 8; ++it) {
        int c = tid + it * 256;
        int r = c >> 5;              // row 0..63
        int q = c & 31;              // 16B chunk in row
        int row = row0 + r; if (row >= n) row = n - 1;
        const unsigned short* srcP;
        int qq;
        if (q < 16) { srcP = Arow + (q >> 2) * ps; qq = q & 3; }
        else        { srcP = Xrow + ((q - 16) >> 2) * ps; qq = (q - 16) & 3; }
        uint4 v = *(const uint4*)(srcP + (size_t)row * 32 + qq * 8);
        *(uint4*)&sA[r * LDK + q * 8] = v;
    }
    __syncthreads();

    int lane = tid & 63;
    int wave = tid >> 6;
    int quad = lane >> 4;
    int tm   = lane & 15;

    f32x4 acc[4][2];
    #pragma unroll
    for (int m = 0; m < 4; ++m)
        #pragma unroll
        for (int j = 0; j < 2; ++j)
            acc[m][j] = (f32x4){0.f, 0.f, 0.f, 0.f};

    const unsigned short* wb0 = Wt + (size_t)(wave * 32 + tm) * 256;

    #pragma unroll
    for (int ks = 0; ks < 8; ++ks) {
        int k0 = ks * 32 + quad * 8;
        bf16x8 a[4], b[2];
        #pragma unroll
        for (int m = 0; m < 4; ++m)
            a[m] = *(const bf16x8*)&sA[(m * 16 + tm) * LDK + k0];
        #pragma unroll
        for (int j = 0; j < 2; ++j)
            b[j] = *(const bf16x8*)(wb0 + (size_t)j * 16 * 256 + k0);
        #pragma unroll
        for (int m = 0; m < 4; ++m)
            #pragma unroll
            for (int j = 0; j < 2; ++j)
                acc[m][j] = __builtin_amdgcn_mfma_f32_16x16x32_bf16(a[m], b[j], acc[m][j], 0, 0, 0);
    }

    // epilogue: C/D col=lane&15 (-> ncol), row=quad*4+reg
    #pragma unroll
    for (int j = 0; j < 2; ++j) {
        int ncol = wave * 32 + j * 16 + tm;
        float bb = bias[ncol];
        #pragma unroll
        for (int m = 0; m < 4; ++m) {
            #pragma unroll
            for (int reg = 0; reg < 4; ++reg) {
                int row = row0 + m * 16 + quad * 4 + reg;
                if (row >= n) continue;
                float v = acc[m][j][reg] + bb;
                if (RELU) v = v > 0.f ? v : 0.f;
                if (OUT_BF16)
                    ((unsigned short*)outp)[(size_t)(ncol >> 5) * ps + row * 32 + (ncol & 31)] = f2b(v);
                else
                    ((float*)outp)[(size_t)row * 128 + ncol] = v;
            }
        }
    }
}

// ---------------------------------------------------------------------------
extern "C" void kernel_launch(void* const* d_in, const int* in_sizes, int n_in,
                              void* d_out, int out_size, void* d_ws, size_t ws_size,
                              hipStream_t stream) {
    const float* x   = (const float*)d_in[0];
    const int*   ei  = (const int*)d_in[1];     // int32 (harness converts int64)
    const float* W1l = (const float*)d_in[2];
    const float* b1  = (const float*)d_in[3];
    const float* W1r = (const float*)d_in[4];
    const float* W2l = (const float*)d_in[5];
    const float* b2  = (const float*)d_in[6];
    const float* W2r = (const float*)d_in[7];
    float* out = (float*)d_out;

    const int D = 128;
    const int N = in_sizes[0] / D;     // 50000
    const int E = in_sizes[1] / 2;     // 800000

    // workspace carve-out (512B aligned), ~32 MB total
    char* ws = (char*)d_ws;
    size_t off = 0;
    auto alloc = [&](size_t bytes) {
        size_t o = off;
        off = (off + bytes + 511) & ~(size_t)511;
        return (void*)(ws + o);
    };
    int*            cursor  = (int*)           alloc((size_t)N * 4);
    unsigned short* edge16  = (unsigned short*)alloc((size_t)N * CAP * 2);
    unsigned short* agg_bf  = (unsigned short*)alloc((size_t)N * D * 2);  // 4 planes
    unsigned short* xb      = (unsigned short*)alloc((size_t)N * D * 2);  // 4 planes
    unsigned short* wt      = (unsigned short*)alloc((size_t)2 * 128 * 256 * 2);
    unsigned short* h_bf = xb;         // gemm1 output aliases xb planes (block-private rows)
    (void)ws_size; (void)n_in; (void)out_size;

    // 1) slot fill, XCD-sharded (cursor doubles as degree)
    zero_kernel<<<(N + 255) / 256, 256, 0, stream>>>(cursor, N);
    {
        int G = 256;                       // chunks per shard; grid = 8*G
        int npg = (N + SH - 1) / SH;       // nodes per shard
        fill_shard_kernel<<<SH * G, 256, 0, stream>>>(ei, cursor, edge16, E, N, G, npg);
    }

    // 2) bf16 conversions: x -> xb planes ; weights -> wt[layer][n][k]
    int n32 = N * D / 4;
    x2b_kernel<<<(n32 + 255) / 256, 256, 0, stream>>>(x, xb, n32, N);
    prep_w_kernel<<<256, 128, 0, stream>>>(W1l, W1r, W2l, W2r, wt);
    const unsigned short* wt1 = wt;
    const unsigned short* wt2 = wt + (size_t)128 * 256;

    int nb4       = (N + 3) / 4;
    int agg_grid  = SLICES * nb4;          // slice is slow-varying blockIdx
    int gemm_grid = (N + 63) / 64;

    // 3) layer 1  (h_bf aliases xb)
    aggregate_kernel<<<agg_grid, 256, 0, stream>>>(xb, cursor, edge16, ei, agg_bf, E, N, nb4);
    gemm_mfma_kernel<1, 1><<<gemm_grid, 256, 0, stream>>>(agg_bf, xb, wt1, b1, (void*)h_bf, N);

    // 4) layer 2
    aggregate_kernel<<<agg_grid, 256, 0, stream>>>(h_bf, cursor, edge16, ei, agg_bf, E, N, nb4);
    gemm_mfma_kernel<0, 0><<<gemm_grid, 256, 0, stream>>>(agg_bf, h_bf, wt2, b2, (void*)out, N);
}

// Round 3
// 229.550 us; speedup vs baseline: 1.3683x; 1.3683x over previous
//
#include <hip/hip_runtime.h>
#include <hip/hip_bf16.h>

typedef __attribute__((ext_vector_type(8))) short bf16x8;
typedef __attribute__((ext_vector_type(4))) float f32x4;
typedef __attribute__((ext_vector_type(2))) float f32x2;

#define CAP 64   // fixed per-node edge slot capacity (deg>CAP -> exact fallback)
#define SH  8    // dst shards (== XCD count; blockIdx%8 ~ XCD heuristic)

// fp32 -> bf16 (round-to-nearest-even), bit pattern as ushort
static __device__ inline unsigned short f2b(float f) {
    unsigned u = __float_as_uint(f);
    unsigned r = (u + 0x7FFFu + ((u >> 16) & 1u)) >> 16;
    return (unsigned short)r;
}
// packed bf16 pair -> two fp32
static __device__ inline float blo(unsigned u) { return __uint_as_float(u << 16); }
static __device__ inline float bhi(unsigned u) { return __uint_as_float(u & 0xFFFF0000u); }

// ---------------------------------------------------------------------------
__global__ void zero_kernel(int* __restrict__ p, int n) {
    int i = blockIdx.x * blockDim.x + threadIdx.x;
    if (i < n) p[i] = 0;
}

// ---------------------------------------------------------------------------
// XCD-sharded slot fill (round-0 proven). cursor[d] ends == in-degree(d).
// ---------------------------------------------------------------------------
__global__ __launch_bounds__(256) void fill_shard_kernel(
        const int* __restrict__ ei, int* __restrict__ cursor,
        unsigned short* __restrict__ edge16, int E, int N, int G, int npg) {
    int s = blockIdx.x & (SH - 1);
    int i = blockIdx.x >> 3;
    int d_lo = s * npg;
    int d_hi = d_lo + npg; if (d_hi > N) d_hi = N;
    int C = (E + G - 1) / G;
    int e0 = i * C;
    int e1 = e0 + C; if (e1 > E) e1 = E;
    for (int e = e0 + threadIdx.x; e < e1; e += 256) {
        int d = ei[E + e];
        if (d < d_lo || d >= d_hi) continue;
        int src = ei[e];
        if ((unsigned)src >= (unsigned)N) src = 0;   // defensive
        int pos = atomicAdd(&cursor[d], 1);
        if (pos < CAP) edge16[(size_t)d * CAP + pos] = (unsigned short)src;
    }
}

// ---------------------------------------------------------------------------
// fp32 x -> bf16 xb (packed, row-major). One float4 -> ushort4 per thread.
// ---------------------------------------------------------------------------
__global__ __launch_bounds__(256) void x2b_kernel(const float* __restrict__ x,
                                                  unsigned short* __restrict__ xb,
                                                  int n4) {
    int i = blockIdx.x * blockDim.x + threadIdx.x;
    if (i >= n4) return;
    float4 v = ((const float4*)x)[i];
    ushort4 b;
    b.x = f2b(v.x); b.y = f2b(v.y); b.z = f2b(v.z); b.w = f2b(v.w);
    ((ushort4*)xb)[i] = b;
}

// ---------------------------------------------------------------------------
// Mean aggregation, GROUP-PER-NODE form (fp32 packed accumulate, bf16 out).
// Block = 256 thr = 4 waves; each wave owns 4 nodes, one 16-lane group each.
// Group g (lanes g*16..g*16+15) processes ALL edges of its node sequentially:
// lane fl covers 16B chunk fl of the 256B row (one uint4 gather per edge).
// NO cross-group reduce (round-1/2 lesson: per-node fixed overhead dominates
// at avg deg 16); epilogue is one full-wave uint4 store (4 rows/inst).
// float2 accumulators -> v_pk_add_f32 on the unpack hot path.
// Fallback (deg > CAP): exact full-edge scan per group (never taken here).
// ---------------------------------------------------------------------------
__global__ __launch_bounds__(256) void aggregate_kernel(
        const unsigned short* __restrict__ in, const int* __restrict__ cursor,
        const unsigned short* __restrict__ edge16, const int* __restrict__ ei,
        unsigned short* __restrict__ agg, int E, int N) {
    int tid  = threadIdx.x;
    int wave = tid >> 6;
    int lane = tid & 63;
    int g    = lane >> 4;        // group (node) within wave
    int fl   = lane & 15;        // 16B chunk within 256B row
    int node = blockIdx.x * 16 + wave * 4 + g;
    if (node >= N) return;
    int deg = cursor[node];

    f32x2 a01 = {0.f, 0.f}, a23 = {0.f, 0.f}, a45 = {0.f, 0.f}, a67 = {0.f, 0.f};

    if (deg <= CAP) {
        const unsigned short* base = edge16 + (size_t)node * CAP;
        // preload up to 64 slot indices: idx[c] holds edge c*16 + fl of this node
        int idx[4];
        #pragma unroll
        for (int c = 0; c < 4; ++c) idx[c] = (int)base[c * 16 + fl];
        #pragma unroll
        for (int c = 0; c < 4; ++c) {
            int j0 = c * 16;
            if (deg <= j0) break;                 // group-uniform
            int jend = deg < j0 + 16 ? deg : j0 + 16;
            for (int j = j0; j < jend; ++j) {
                int s = __shfl(idx[c], (g << 4) | (j - j0));
                const uint4 v = *(const uint4*)(in + (size_t)s * 128 + fl * 8);
                a01 += (f32x2){blo(v.x), bhi(v.x)};
                a23 += (f32x2){blo(v.y), bhi(v.y)};
                a45 += (f32x2){blo(v.z), bhi(v.z)};
                a67 += (f32x2){blo(v.w), bhi(v.w)};
            }
        }
    } else {
        // exact fallback: group scans the whole edge list for its node
        for (int j = 0; j < E; ++j) {
            if (ei[E + j] == node) {
                int s = ei[j];
                if ((unsigned)s >= (unsigned)N) s = 0;
                const uint4 v = *(const uint4*)(in + (size_t)s * 128 + fl * 8);
                a01 += (f32x2){blo(v.x), bhi(v.x)};
                a23 += (f32x2){blo(v.y), bhi(v.y)};
                a45 += (f32x2){blo(v.z), bhi(v.z)};
                a67 += (f32x2){blo(v.w), bhi(v.w)};
            }
        }
    }

    float inv = 1.0f / (float)(deg > 1 ? deg : 1);
    uint4 o;
    o.x = (unsigned)f2b(a01.x * inv) | ((unsigned)f2b(a01.y * inv) << 16);
    o.y = (unsigned)f2b(a23.x * inv) | ((unsigned)f2b(a23.y * inv) << 16);
    o.z = (unsigned)f2b(a45.x * inv) | ((unsigned)f2b(a45.y * inv) << 16);
    o.w = (unsigned)f2b(a67.x * inv) | ((unsigned)f2b(a67.y * inv) << 16);
    *(uint4*)(agg + (size_t)node * 128 + fl * 8) = o;   // full-wave store: 4 rows
}

// ---------------------------------------------------------------------------
// Weight prep (once per call): Wt[layer][n][k] bf16, k-contiguous (transposed)
// k<128 -> Wl[k][n], k>=128 -> Wr[k-128][n]. 64KB per layer.
// ---------------------------------------------------------------------------
__global__ void prep_w_kernel(const float* __restrict__ W1l, const float* __restrict__ W1r,
                              const float* __restrict__ W2l, const float* __restrict__ W2r,
                              unsigned short* __restrict__ wt) {
    int n = blockIdx.x & 127;
    int layer = blockIdx.x >> 7;
    int k = threadIdx.x;           // 0..127
    const float* Wlp = layer ? W2l : W1l;
    const float* Wrp = layer ? W2r : W1r;
    unsigned short* dst = wt + (size_t)layer * 128 * 256 + (size_t)n * 256;
    dst[k]       = f2b(Wlp[(size_t)k * 128 + n]);
    dst[k + 128] = f2b(Wrp[(size_t)k * 128 + n]);
}

// ---------------------------------------------------------------------------
// MFMA GEMM (round-0 proven): out[i,:] = (agg[i,:] || x[i,:]) @ Wt^T + bias.
// M-tile 64 rows/block, 4 waves; wave w covers n in [32w, 32w+32).
// OUT_BF16=1: writes ushort h (may alias Xrow: block-private rows staged to
// LDS before any store).
// ---------------------------------------------------------------------------
template<int RELU, int OUT_BF16>
__global__ __launch_bounds__(256) void gemm_mfma_kernel(
        const unsigned short* __restrict__ Arow, const unsigned short* __restrict__ Xrow,
        const unsigned short* __restrict__ Wt, const float* __restrict__ bias,
        void* __restrict__ outp, int n) {
    constexpr int LDK = 264;
    __shared__ unsigned short sA[64 * LDK];
    int tid = threadIdx.x;
    int row0 = blockIdx.x * 64;

    // stage 64 rows x 256 bf16 = 2048 x 16B chunks, 8/thread
    #pragma unroll
    for (int it = 0; it < 8; ++it) {
        int c = tid + it * 256;
        int r = c >> 5;              // row 0..63
        int q = c & 31;              // 16B chunk in row
        int row = row0 + r; if (row >= n) row = n - 1;
        uint4 v = (q < 16) ? ((const uint4*)(Arow + (size_t)row * 128))[q]
                           : ((const uint4*)(Xrow + (size_t)row * 128))[q - 16];
        *(uint4*)&sA[r * LDK + q * 8] = v;
    }
    __syncthreads();

    int lane = tid & 63;
    int wave = tid >> 6;
    int quad = lane >> 4;
    int tm   = lane & 15;

    f32x4 acc[4][2];
    #pragma unroll
    for (int m = 0; m < 4; ++m)
        #pragma unroll
        for (int j = 0; j < 2; ++j)
            acc[m][j] = (f32x4){0.f, 0.f, 0.f, 0.f};

    const unsigned short* wb0 = Wt + (size_t)(wave * 32 + tm) * 256;

    #pragma unroll
    for (int ks = 0; ks < 8; ++ks) {
        int k0 = ks * 32 + quad * 8;
        bf16x8 a[4], b[2];
        #pragma unroll
        for (int m = 0; m < 4; ++m)
            a[m] = *(const bf16x8*)&sA[(m * 16 + tm) * LDK + k0];
        #pragma unroll
        for (int j = 0; j < 2; ++j)
            b[j] = *(const bf16x8*)(wb0 + (size_t)j * 16 * 256 + k0);
        #pragma unroll
        for (int m = 0; m < 4; ++m)
            #pragma unroll
            for (int j = 0; j < 2; ++j)
                acc[m][j] = __builtin_amdgcn_mfma_f32_16x16x32_bf16(a[m], b[j], acc[m][j], 0, 0, 0);
    }

    // epilogue: C/D col=lane&15 (-> ncol), row=quad*4+reg
    #pragma unroll
    for (int j = 0; j < 2; ++j) {
        int ncol = wave * 32 + j * 16 + tm;
        float bb = bias[ncol];
        #pragma unroll
        for (int m = 0; m < 4; ++m) {
            #pragma unroll
            for (int reg = 0; reg < 4; ++reg) {
                int row = row0 + m * 16 + quad * 4 + reg;
                if (row >= n) continue;
                float v = acc[m][j][reg] + bb;
                if (RELU) v = v > 0.f ? v : 0.f;
                if (OUT_BF16)
                    ((unsigned short*)outp)[(size_t)row * 128 + ncol] = f2b(v);
                else
                    ((float*)outp)[(size_t)row * 128 + ncol] = v;
            }
        }
    }
}

// ---------------------------------------------------------------------------
extern "C" void kernel_launch(void* const* d_in, const int* in_sizes, int n_in,
                              void* d_out, int out_size, void* d_ws, size_t ws_size,
                              hipStream_t stream) {
    const float* x   = (const float*)d_in[0];
    const int*   ei  = (const int*)d_in[1];     // int32 (harness converts int64)
    const float* W1l = (const float*)d_in[2];
    const float* b1  = (const float*)d_in[3];
    const float* W1r = (const float*)d_in[4];
    const float* W2l = (const float*)d_in[5];
    const float* b2  = (const float*)d_in[6];
    const float* W2r = (const float*)d_in[7];
    float* out = (float*)d_out;

    const int D = 128;
    const int N = in_sizes[0] / D;     // 50000
    const int E = in_sizes[1] / 2;     // 800000

    // workspace carve-out (512B aligned), ~32 MB total
    char* ws = (char*)d_ws;
    size_t off = 0;
    auto alloc = [&](size_t bytes) {
        size_t o = off;
        off = (off + bytes + 511) & ~(size_t)511;
        return (void*)(ws + o);
    };
    int*            cursor  = (int*)           alloc((size_t)N * 4);
    unsigned short* edge16  = (unsigned short*)alloc((size_t)N * CAP * 2);
    unsigned short* agg_bf  = (unsigned short*)alloc((size_t)N * D * 2);
    unsigned short* xb      = (unsigned short*)alloc((size_t)N * D * 2);
    unsigned short* wt      = (unsigned short*)alloc((size_t)2 * 128 * 256 * 2);
    unsigned short* h_bf = xb;         // gemm1 output aliases xb (block-private rows)
    (void)ws_size; (void)n_in; (void)out_size;

    // 1) slot fill, XCD-sharded (cursor doubles as degree)
    zero_kernel<<<(N + 255) / 256, 256, 0, stream>>>(cursor, N);
    {
        int G = 256;                       // chunks per shard; grid = 8*G
        int npg = (N + SH - 1) / SH;       // nodes per shard
        fill_shard_kernel<<<SH * G, 256, 0, stream>>>(ei, cursor, edge16, E, N, G, npg);
    }

    // 2) bf16 conversions: x -> xb ; weights -> wt[layer][n][k]
    int n4 = N * D / 4;
    x2b_kernel<<<(n4 + 255) / 256, 256, 0, stream>>>(x, xb, n4);
    prep_w_kernel<<<256, 128, 0, stream>>>(W1l, W1r, W2l, W2r, wt);
    const unsigned short* wt1 = wt;
    const unsigned short* wt2 = wt + (size_t)128 * 256;

    int agg_grid  = (N + 15) / 16;     // 16 nodes per 256-thread block
    int gemm_grid = (N + 63) / 64;

    // 3) layer 1  (h_bf aliases xb)
    aggregate_kernel<<<agg_grid, 256, 0, stream>>>(xb, cursor, edge16, ei, agg_bf, E, N);
    gemm_mfma_kernel<1, 1><<<gemm_grid, 256, 0, stream>>>(agg_bf, xb, wt1, b1, (void*)h_bf, N);

    // 4) layer 2
    aggregate_kernel<<<agg_grid, 256, 0, stream>>>(h_bf, cursor, edge16, ei, agg_bf, E, N);
    gemm_mfma_kernel<0, 0><<<gemm_grid, 256, 0, stream>>>(agg_bf, h_bf, wt2, b2, (void*)out, N);
}